// Round 2
// 678.319 us; speedup vs baseline: 1.0341x; 1.0341x over previous
//
#include <hip/hip_runtime.h>
#include <hip/hip_fp16.h>

#define M_SZ 4096
#define I_SZ 2048
#define H_SZ 2048
#define K_SZ 4096   // I + H
#define N_SZ 8192   // 4 * H

typedef _Float16 half8_t __attribute__((ext_vector_type(8)));
typedef _Float16 half4_t __attribute__((ext_vector_type(4)));
typedef float    f32x4   __attribute__((ext_vector_type(4)));

typedef const void __attribute__((address_space(1)))* gas_ptr;
typedef void       __attribute__((address_space(3)))* las_ptr;

__device__ __forceinline__ void async_load16(const void* g, void* l) {
    // width-16 global->LDS DMA; LDS dest is wave-uniform base + lane*16
    __builtin_amdgcn_global_load_lds((gas_ptr)g, (las_ptr)l, 16, 0, 0);
}

__device__ __forceinline__ float fexp(float x) {
    return __builtin_amdgcn_exp2f(x * 1.44269504088896340736f);
}
__device__ __forceinline__ float frcp(float x) { return __builtin_amdgcn_rcpf(x); }
__device__ __forceinline__ float flog1p(float t) {
    // log(1+t), t in (0,1]; log2 then scale. abs err ~1e-7 at small t via 1+t rounding.
    return __builtin_amdgcn_logf(1.0f + t) * 0.69314718055994530942f;
}

// ---------------------------------------------------------------------------
// Kernel 1: combined = concat(x, h) cast to fp16, row-major [4096][4096]
// ---------------------------------------------------------------------------
__global__ void cast_combined_kernel(const float* __restrict__ x,
                                     const float* __restrict__ h,
                                     _Float16* __restrict__ A) {
    int idx = blockIdx.x * 256 + threadIdx.x;   // one float4 each
    int b   = idx >> 10;
    int c4  = idx & 1023;
    const float* src = (c4 < 512) ? (x + (size_t)b * I_SZ + c4 * 4)
                                  : (h + (size_t)b * H_SZ + (c4 - 512) * 4);
    f32x4 v = *(const f32x4*)src;
    half4_t o = { (_Float16)v[0], (_Float16)v[1], (_Float16)v[2], (_Float16)v[3] };
    *(half4_t*)(A + (size_t)b * K_SZ + c4 * 4) = o;
}

// ---------------------------------------------------------------------------
// Kernel 2: Wt[n][k] = (fp16) W[k][n].  64k x 64n tile via LDS.
// Phase 1: float4 reads along n (coalesced 256B/row-group), in-register 4x4
//   micro-transpose (thread owns k0..k0+3 x n4..n4+3), half4 (8B) LDS writes.
// Phase 2: two chunk-swizzled half4 LDS reads -> half8 (16B) global store.
// LDS row = 64 fp16 = 128B = 16 chunks of 8B; chunk' = chunk ^ (n&15) makes
// both the b64 writes and b64 reads hit the inherent 4-way floor (= full BW).
// VMEM loads: 8.4M dwordx4 (was 33.5M scalar dword) — issue-bound fix.
// ---------------------------------------------------------------------------
__global__ __launch_bounds__(256)
void transpose_cast_W(const float* __restrict__ W,
                      _Float16* __restrict__ Wt) {
    __shared__ _Float16 sT[64 * 64];
    const int t  = threadIdx.x;
    const int nb = blockIdx.x * 64;
    const int kb = blockIdx.y * 64;
    const int k0 = (t >> 4) * 4;          // 0..60 step 4
    const int n4 = (t & 15) * 4;          // 0..60 step 4

    f32x4 v[4];
#pragma unroll
    for (int p = 0; p < 4; ++p)
        v[p] = *(const f32x4*)(W + (size_t)(kb + k0 + p) * N_SZ + nb + n4);
#pragma unroll
    for (int j = 0; j < 4; ++j) {
        half4_t hv = { (_Float16)v[0][j], (_Float16)v[1][j],
                       (_Float16)v[2][j], (_Float16)v[3][j] };
        const int n = n4 + j;
        const int c = (k0 >> 2) ^ (n & 15);
        *(half4_t*)(sT + n * 64 + c * 4) = hv;
    }
    __syncthreads();
#pragma unroll
    for (int p = 0; p < 2; ++p) {
        const int n  = (t >> 3) + p * 32;
        const int c0 = ((t & 7) * 2)     ^ (n & 15);
        const int c1 = ((t & 7) * 2 + 1) ^ (n & 15);
        half4_t lo = *(const half4_t*)(sT + n * 64 + c0 * 4);
        half4_t hi = *(const half4_t*)(sT + n * 64 + c1 * 4);
        half8_t o = { lo[0], lo[1], lo[2], lo[3], hi[0], hi[1], hi[2], hi[3] };
        *(half8_t*)(Wt + (size_t)(nb + n) * K_SZ + kb + (t & 7) * 8) = o;
    }
}

// ---------------------------------------------------------------------------
// Kernel 3: fused GEMM + sLSTM pointwise.
// Tile: 128 m x 128 cols. B-tile row r -> Wt row n(r) = ((r>>4)&3)*2048 +
//   j0 + (r&15) + (r>>6)*16  (4 gates x 16 j per 64-row half; n(r+64)=n(r)+16).
// Waves 2x2: wave covers 64m x 64col (all 4 gates x 16 j) with 4x4 fragments
//   -> 8 ds_read_b128 per 16 MFMA (was 10) => 32 KiB LDS reads/blk/K-step.
// Thread owning z(m,j) in acc[mi][0] owns i,f,o in acc[mi][1..3] -> in-reg fusion.
// LDS XOR swizzle unchanged: chunk c of row r at slot c ^ ((r>>1)&3).
// ---------------------------------------------------------------------------
__global__ __launch_bounds__(256)
void gemm_fused_kernel(const _Float16* __restrict__ A,
                       const _Float16* __restrict__ Wt,
                       const float* __restrict__ Bias,
                       const float* __restrict__ Cst,
                       const float* __restrict__ Nst,
                       const float* __restrict__ Mst,
                       float* __restrict__ out) {
    __shared__ _Float16 sA[128 * 32];
    __shared__ _Float16 sB[128 * 32];
    const int t    = threadIdx.x;
    const int wave = t >> 6;
    const int lane = t & 63;
    const int m0 = blockIdx.y * 128;
    const int j0 = blockIdx.x * 32;

    f32x4 acc[4][4] = {};

    // ---- staging lane mapping (store side of the XOR swizzle) ----
    const int srl   = lane >> 2;                        // sub-row 0..15
    const int chunk = (lane & 3) ^ ((lane >> 3) & 3);   // global k-chunk this lane fetches
    const int ar0 = wave * 16 + srl;                    // A row, issue 0 (0..63)
    const int br0 = wave * 16 + srl;                    // B tile-row, issue 0 (0..63)
    const int gb  = (br0 >> 4) & 3;                     // gate of this B row
    const int wrow0 = gb * H_SZ + j0 + (br0 & 15);      // n(br0); n(br0+64) = +16

    const _Float16* gA0 = A  + (size_t)(m0 + ar0) * K_SZ + chunk * 8;
    const _Float16* gA1 = gA0 + (size_t)64 * K_SZ;
    const _Float16* gB0 = Wt + (size_t)wrow0 * K_SZ + chunk * 8;
    const _Float16* gB1 = gB0 + (size_t)16 * K_SZ;
    char* lA0 = (char*)sA + wave * 1024;
    char* lA1 = lA0 + 4096;
    char* lB0 = (char*)sB + wave * 1024;
    char* lB1 = lB0 + 4096;

    // ---- fragment read addresses (read side of the swizzle) ----
    const int lm    = lane & 15;
    const int slot  = (lane >> 4) ^ ((lm >> 1) & 3);    // per-lane constant
    const int wm    = (wave >> 1) * 64;                 // wave m-offset
    const int jhalf = wave & 1;                         // wave j-half (16 cols)
    const _Float16* fA = sA + (wm + lm) * 32 + slot * 8;
    const _Float16* fB = sB + (jhalf * 64 + lm) * 32 + slot * 8;

    for (int k0 = 0; k0 < K_SZ; k0 += 32) {
        async_load16(gA0 + k0, lA0);
        async_load16(gA1 + k0, lA1);
        async_load16(gB0 + k0, lB0);
        async_load16(gB1 + k0, lB1);
        __syncthreads();

        half8_t af[4], bf[4];
#pragma unroll
        for (int mi = 0; mi < 4; ++mi)
            af[mi] = *(const half8_t*)(fA + mi * 16 * 32);
#pragma unroll
        for (int ni = 0; ni < 4; ++ni)
            bf[ni] = *(const half8_t*)(fB + ni * 16 * 32);
#pragma unroll
        for (int mi = 0; mi < 4; ++mi)
#pragma unroll
            for (int ni = 0; ni < 4; ++ni)
                acc[mi][ni] = __builtin_amdgcn_mfma_f32_16x16x32_f16(
                    af[mi], bf[ni], acc[mi][ni], 0, 0, 0);
        __syncthreads();
    }

    // ---- fused epilogue: C/D layout col=lane&15, row=(lane>>4)*4+reg ----
    const int cr = (lane >> 4) * 4;
    const int cc = lane & 15;
    const int jcol = j0 + jhalf * 16 + cc;
    const size_t bh = (size_t)M_SZ * H_SZ;
    const float bz  = Bias[jcol];
    const float bi  = Bias[H_SZ + jcol];
    const float bff = Bias[2 * H_SZ + jcol];
    const float bo  = Bias[3 * H_SZ + jcol];
#pragma unroll
    for (int mi = 0; mi < 4; ++mi) {
#pragma unroll
        for (int r = 0; r < 4; ++r) {
            const int m = m0 + wm + mi * 16 + cr + r;
            const size_t off = (size_t)m * H_SZ + jcol;
            float z = acc[mi][0][r] + bz;
            float i = acc[mi][1][r] + bi;
            float f = acc[mi][2][r] + bff;
            float o = acc[mi][3][r] + bo;
            float z_t = 1.0f - 2.0f * frcp(fexp(2.0f * z) + 1.0f);
            float f_t = frcp(1.0f + fexp(-f));
            float o_t = frcp(1.0f + fexp(-o));
            float ls  = fminf(f, 0.0f) - flog1p(fexp(-fabsf(f)));
            float m_t = fmaxf(ls + Mst[off], i);
            float ip  = fexp(i - m_t);
            float c_t = f_t * Cst[off] + ip * z_t;
            float n_t = f_t * Nst[off] + ip;
            float h_t = o_t * c_t * frcp(n_t);
            out[off]          = h_t;
            out[bh + off]     = c_t;
            out[2 * bh + off] = n_t;
            out[3 * bh + off] = m_t;
        }
    }
}

// ---------------------------------------------------------------------------
extern "C" void kernel_launch(void* const* d_in, const int* in_sizes, int n_in,
                              void* d_out, int out_size, void* d_ws, size_t ws_size,
                              hipStream_t stream) {
    const float* x    = (const float*)d_in[0];
    const float* h    = (const float*)d_in[1];
    const float* c    = (const float*)d_in[2];
    const float* n    = (const float*)d_in[3];
    const float* m    = (const float*)d_in[4];
    const float* W    = (const float*)d_in[5];
    const float* Bias = (const float*)d_in[6];
    float* out = (float*)d_out;

    // ws layout: Wt fp16 (64 MiB) | combined fp16 (32 MiB)
    const size_t WT_BYTES = (size_t)N_SZ * K_SZ * 2;
    const size_t A_BYTES  = (size_t)M_SZ * K_SZ * 2;
    if (ws_size < WT_BYTES + A_BYTES) return;

    char* ws = (char*)d_ws;
    _Float16* Wt = (_Float16*)ws;
    _Float16* A  = (_Float16*)(ws + WT_BYTES);

    cast_combined_kernel<<<16384, 256, 0, stream>>>(x, h, A);
    transpose_cast_W<<<dim3(128, 64), 256, 0, stream>>>(W, Wt);
    gemm_fused_kernel<<<dim3(64, 32), 256, 0, stream>>>(A, Wt, Bias, c, n, m, out);
}

// Round 4
// 575.090 us; speedup vs baseline: 1.2197x; 1.1795x over previous
//
#include <hip/hip_runtime.h>
#include <hip/hip_fp16.h>

#define M_SZ 4096
#define I_SZ 2048
#define H_SZ 2048
#define K_SZ 4096   // I + H
#define N_SZ 8192   // 4 * H

typedef _Float16 half8_t __attribute__((ext_vector_type(8)));
typedef _Float16 half4_t __attribute__((ext_vector_type(4)));
typedef float    f32x4   __attribute__((ext_vector_type(4)));

typedef const void __attribute__((address_space(1)))* gas_ptr;
typedef void       __attribute__((address_space(3)))* las_ptr;

__device__ __forceinline__ void async_load16(const void* g, void* l) {
    // width-16 global->LDS DMA; LDS dest is wave-uniform base + lane*16
    __builtin_amdgcn_global_load_lds((gas_ptr)g, (las_ptr)l, 16, 0, 0);
}

__device__ __forceinline__ float fexp(float x) {
    return __builtin_amdgcn_exp2f(x * 1.44269504088896340736f);
}
__device__ __forceinline__ float frcp(float x) { return __builtin_amdgcn_rcpf(x); }
__device__ __forceinline__ float flog1p(float t) {
    return __builtin_amdgcn_logf(1.0f + t) * 0.69314718055994530942f;
}

// ---------------------------------------------------------------------------
// Kernel 1: combined = concat(x, h) cast to fp16, row-major [4096][4096]
// ---------------------------------------------------------------------------
__global__ void cast_combined_kernel(const float* __restrict__ x,
                                     const float* __restrict__ h,
                                     _Float16* __restrict__ A) {
    int idx = blockIdx.x * 256 + threadIdx.x;   // one float4 each
    int b   = idx >> 10;
    int c4  = idx & 1023;
    const float* src = (c4 < 512) ? (x + (size_t)b * I_SZ + c4 * 4)
                                  : (h + (size_t)b * H_SZ + (c4 - 512) * 4);
    f32x4 v = *(const f32x4*)src;
    half4_t o = { (_Float16)v[0], (_Float16)v[1], (_Float16)v[2], (_Float16)v[3] };
    *(half4_t*)(A + (size_t)b * K_SZ + c4 * 4) = o;
}

// ---------------------------------------------------------------------------
// Kernel 2: Wt[n][k] = (fp16) W[k][n].  64k x 64n tile via LDS (unchanged).
// ---------------------------------------------------------------------------
__global__ __launch_bounds__(256)
void transpose_cast_W(const float* __restrict__ W,
                      _Float16* __restrict__ Wt) {
    __shared__ _Float16 sT[64 * 64];
    const int t  = threadIdx.x;
    const int nb = blockIdx.x * 64;
    const int kb = blockIdx.y * 64;
    const int k0 = (t >> 4) * 4;
    const int n4 = (t & 15) * 4;

    f32x4 v[4];
#pragma unroll
    for (int p = 0; p < 4; ++p)
        v[p] = *(const f32x4*)(W + (size_t)(kb + k0 + p) * N_SZ + nb + n4);
#pragma unroll
    for (int j = 0; j < 4; ++j) {
        half4_t hv = { (_Float16)v[0][j], (_Float16)v[1][j],
                       (_Float16)v[2][j], (_Float16)v[3][j] };
        const int n = n4 + j;
        const int c = (k0 >> 2) ^ (n & 15);
        *(half4_t*)(sT + n * 64 + c * 4) = hv;
    }
    __syncthreads();
#pragma unroll
    for (int p = 0; p < 2; ++p) {
        const int n  = (t >> 3) + p * 32;
        const int c0 = ((t & 7) * 2)     ^ (n & 15);
        const int c1 = ((t & 7) * 2 + 1) ^ (n & 15);
        half4_t lo = *(const half4_t*)(sT + n * 64 + c0 * 4);
        half4_t hi = *(const half4_t*)(sT + n * 64 + c1 * 4);
        half8_t o = { lo[0], lo[1], lo[2], lo[3], hi[0], hi[1], hi[2], hi[3] };
        *(half8_t*)(Wt + (size_t)(nb + n) * K_SZ + kb + (t & 7) * 8) = o;
    }
}

// ---------------------------------------------------------------------------
// Kernel 3a (FALLBACK, R2-passing): 128x128 2-phase fused GEMM + pointwise.
// ---------------------------------------------------------------------------
__global__ __launch_bounds__(256)
void gemm_fused_kernel(const _Float16* __restrict__ A,
                       const _Float16* __restrict__ Wt,
                       const float* __restrict__ Bias,
                       const float* __restrict__ Cst,
                       const float* __restrict__ Nst,
                       const float* __restrict__ Mst,
                       float* __restrict__ out) {
    __shared__ _Float16 sA[128 * 32];
    __shared__ _Float16 sB[128 * 32];
    const int t    = threadIdx.x;
    const int wave = t >> 6;
    const int lane = t & 63;
    const int m0 = blockIdx.y * 128;
    const int j0 = blockIdx.x * 32;

    f32x4 acc[4][4] = {};

    const int srl   = lane >> 2;
    const int chunk = (lane & 3) ^ ((lane >> 3) & 3);
    const int ar0 = wave * 16 + srl;
    const int br0 = wave * 16 + srl;
    const int gb  = (br0 >> 4) & 3;
    const int wrow0 = gb * H_SZ + j0 + (br0 & 15);

    const _Float16* gA0 = A  + (size_t)(m0 + ar0) * K_SZ + chunk * 8;
    const _Float16* gA1 = gA0 + (size_t)64 * K_SZ;
    const _Float16* gB0 = Wt + (size_t)wrow0 * K_SZ + chunk * 8;
    const _Float16* gB1 = gB0 + (size_t)16 * K_SZ;
    char* lA0 = (char*)sA + wave * 1024;
    char* lA1 = lA0 + 4096;
    char* lB0 = (char*)sB + wave * 1024;
    char* lB1 = lB0 + 4096;

    const int lm    = lane & 15;
    const int slot  = (lane >> 4) ^ ((lm >> 1) & 3);
    const int wm    = (wave >> 1) * 64;
    const int jhalf = wave & 1;
    const _Float16* fA = sA + (wm + lm) * 32 + slot * 8;
    const _Float16* fB = sB + (jhalf * 64 + lm) * 32 + slot * 8;

    for (int k0 = 0; k0 < K_SZ; k0 += 32) {
        async_load16(gA0 + k0, lA0);
        async_load16(gA1 + k0, lA1);
        async_load16(gB0 + k0, lB0);
        async_load16(gB1 + k0, lB1);
        __syncthreads();

        half8_t af[4], bf[4];
#pragma unroll
        for (int mi = 0; mi < 4; ++mi)
            af[mi] = *(const half8_t*)(fA + mi * 16 * 32);
#pragma unroll
        for (int ni = 0; ni < 4; ++ni)
            bf[ni] = *(const half8_t*)(fB + ni * 16 * 32);
#pragma unroll
        for (int mi = 0; mi < 4; ++mi)
#pragma unroll
            for (int ni = 0; ni < 4; ++ni)
                acc[mi][ni] = __builtin_amdgcn_mfma_f32_16x16x32_f16(
                    af[mi], bf[ni], acc[mi][ni], 0, 0, 0);
        __syncthreads();
    }

    const int cr = (lane >> 4) * 4;
    const int cc = lane & 15;
    const int jcol = j0 + jhalf * 16 + cc;
    const size_t bh = (size_t)M_SZ * H_SZ;
    const float bz  = Bias[jcol];
    const float bi  = Bias[H_SZ + jcol];
    const float bff = Bias[2 * H_SZ + jcol];
    const float bo  = Bias[3 * H_SZ + jcol];
#pragma unroll
    for (int mi = 0; mi < 4; ++mi) {
#pragma unroll
        for (int r = 0; r < 4; ++r) {
            const int m = m0 + wm + mi * 16 + cr + r;
            const size_t off = (size_t)m * H_SZ + jcol;
            float z = acc[mi][0][r] + bz;
            float i = acc[mi][1][r] + bi;
            float f = acc[mi][2][r] + bff;
            float o = acc[mi][3][r] + bo;
            float z_t = 1.0f - 2.0f * frcp(fexp(2.0f * z) + 1.0f);
            float f_t = frcp(1.0f + fexp(-f));
            float o_t = frcp(1.0f + fexp(-o));
            float ls  = fminf(f, 0.0f) - flog1p(fexp(-fabsf(f)));
            float m_t = fmaxf(ls + Mst[off], i);
            float ip  = fexp(i - m_t);
            float c_t = f_t * Cst[off] + ip * z_t;
            float n_t = f_t * Nst[off] + ip;
            float h_t = o_t * c_t * frcp(n_t);
            out[off]          = h_t;
            out[bh + off]     = c_t;
            out[2 * bh + off] = n_t;
            out[3 * bh + off] = m_t;
        }
    }
}

// ---------------------------------------------------------------------------
// Kernel 3b: 256x256 8-phase fused GEMM + sLSTM pointwise (T1+T2+T3+T4+T5).
//
// Tile 256m x 256cols (64 j x 4 gates), BK=64, 8 waves (2M x 4N), 512 thr.
// B tile row r -> Wt row n(r) = ((r>>4)&3)*2048 + j0 + (r&15) + (r>>6)*16
//   (4 gates x 16 j per 64-row quarter => wave wc owns j-range wc*16..+16,
//    all 4 gates; frag ni == gate -> in-register z/i/f/o fusion).
// LDS 128 KiB: 2 dbuf x [256 rows][64 k] x (A,B). Rows = 128 B = 8 chunks
//   of 16 B; chunk c of row r stored at slot c^(r&7) (T2) via pre-swizzled
//   GLOBAL source (global_load_lds writes linearly); read slot (ks*4+lg)^(lm&7).
// Phases (per iter = 2 K-tiles E=buf0, O=buf1):
//   P1 rd A0(qm0)+B0(qn0), stage A1a(kO) | P2 rd B0(qn1), stage A1b(kO)
//   P3 rd A0(qm1), stage B0a(kE2)        | P4 -, stage B0b(kE2), vmcnt(4)
//   P5 rd A1(qm0)+B1(qn0), stage A0a(kE2)| P6 rd B1(qn1), stage A0b(kE2)
//   P7 rd A1(qm1), stage B1a(kO2)        | P8 -, stage B1b(kO2), vmcnt(4)
// Every region is restaged >=1 barrier after its last reader; vmcnt(4)
// leaves the 2 newest half-tiles in flight (counted, never 0).
// ---------------------------------------------------------------------------
#define BAR() __builtin_amdgcn_s_barrier()

#define LOAD_A(d, qm) do { \
    _Pragma("unroll") \
    for (int mi_ = 0; mi_ < 4; ++mi_) { \
        const _Float16* p_ = sA + (d)*16384 + (wr*128 + ((qm)*4+mi_)*16 + lm)*64; \
        a[mi_][0] = *(const half8_t*)(p_ + slot0*8); \
        a[mi_][1] = *(const half8_t*)(p_ + slot1*8); \
    } } while(0)

#define LOAD_B(d, qn) do { \
    _Pragma("unroll") \
    for (int ni_ = 0; ni_ < 2; ++ni_) { \
        const _Float16* p_ = sB + (d)*16384 + (wc*64 + ((qn)*2+ni_)*16 + lm)*64; \
        b[(qn)*2+ni_][0] = *(const half8_t*)(p_ + slot0*8); \
        b[(qn)*2+ni_][1] = *(const half8_t*)(p_ + slot1*8); \
    } } while(0)

#define MFMA8(qm, qn) do { \
    __builtin_amdgcn_s_setprio(1); \
    _Pragma("unroll") \
    for (int mi_ = 0; mi_ < 4; ++mi_) { \
        _Pragma("unroll") \
        for (int ni_ = 0; ni_ < 2; ++ni_) { \
            acc[(qm)*4+mi_][(qn)*2+ni_] = __builtin_amdgcn_mfma_f32_16x16x32_f16( \
                a[mi_][0], b[(qn)*2+ni_][0], acc[(qm)*4+mi_][(qn)*2+ni_], 0, 0, 0); \
            acc[(qm)*4+mi_][(qn)*2+ni_] = __builtin_amdgcn_mfma_f32_16x16x32_f16( \
                a[mi_][1], b[(qn)*2+ni_][1], acc[(qm)*4+mi_][(qn)*2+ni_], 0, 0, 0); \
        } } \
    __builtin_amdgcn_s_setprio(0); \
} while(0)

#define STAGE_A(d, h, kt) do { \
    char* ba_ = (char*)sA + (d)*32768 + ((h)*128 + wid*16)*128; \
    async_load16(pA0 + (size_t)(h)*(128*K_SZ) + (kt), ba_); \
    async_load16(pA1 + (size_t)(h)*(128*K_SZ) + (kt), ba_ + 1024); \
} while(0)

#define STAGE_B(d, h, kt) do { \
    char* bb_ = (char*)sB + (d)*32768 + ((h)*128 + wid*16)*128; \
    async_load16(pB0 + (size_t)(h)*(32*K_SZ) + (kt), bb_); \
    async_load16(pB1 + (size_t)(h)*(32*K_SZ) + (kt), bb_ + 1024); \
} while(0)

#define VMCNT4() do { \
    asm volatile("s_waitcnt vmcnt(4)" ::: "memory"); \
} while(0)

__global__ __launch_bounds__(512, 2)
void gemm8_fused(const _Float16* __restrict__ A,
                 const _Float16* __restrict__ Wt,
                 const float* __restrict__ Bias,
                 const float* __restrict__ Cst,
                 const float* __restrict__ Nst,
                 const float* __restrict__ Mst,
                 float* __restrict__ out) {
    extern __shared__ char lds[];
    _Float16* sA = (_Float16*)lds;                 // [2][256][64]
    _Float16* sB = (_Float16*)(lds + 65536);       // [2][256][64]

    const int t    = threadIdx.x;
    const int wid  = t >> 6;
    const int lane = t & 63;

    // T1: XCD-aware block swizzle (512 wgs, 512%8==0 -> bijective)
    const int flat = blockIdx.y * 32 + blockIdx.x;
    const int swz  = (flat & 7) * 64 + (flat >> 3);
    const int m0 = (swz >> 5) * 256;
    const int j0 = (swz & 31) * 64;

    const int wr = wid >> 2, wc = wid & 3;
    const int lm = lane & 15, lg = lane >> 4;
    const int slot0 = lg ^ (lm & 7);          // read slot, ks=0
    const int slot1 = slot0 ^ 4;              // ks=1

    f32x4 acc[8][4] = {};
    half8_t a[4][2], b[4][2];

    // ---- staging source addrs (pre-swizzled: lane fetches chunk (l&7)^(l>>3)) ----
    const int l8 = lane >> 3, s8 = lane & 7;
    const int cS = s8 ^ l8;                   // global k-chunk this lane fetches
    const int rq0 = wid * 16 + l8;            // row-in-half, load q=0
    const int rq1 = rq0 + 8;                  // load q=1
    const int nB0 = ((rq0 >> 4) & 3) * H_SZ + j0 + (rq0 & 15) + (rq0 >> 6) * 16;
    const int nB1 = ((rq1 >> 4) & 3) * H_SZ + j0 + (rq1 & 15) + (rq1 >> 6) * 16;

    const _Float16* pA0 = A  + (size_t)(m0 + rq0) * K_SZ + cS * 8;
    const _Float16* pA1 = A  + (size_t)(m0 + rq1) * K_SZ + cS * 8;
    const _Float16* pB0 = Wt + (size_t)nB0 * K_SZ + cS * 8;
    const _Float16* pB1 = Wt + (size_t)nB1 * K_SZ + cS * 8;

    // ---- prologue: tile0 (buf0, all 4 halves) + tile1 B halves (buf1) ----
    STAGE_A(0, 0, 0);  STAGE_A(0, 1, 0);
    STAGE_B(0, 0, 0);  STAGE_B(0, 1, 0);
    STAGE_B(1, 0, 64); STAGE_B(1, 1, 64);
    VMCNT4();
    BAR();
    __builtin_amdgcn_sched_barrier(0);

#pragma unroll 1
    for (int i = 0; i < 32; ++i) {
        const int kO  = (2 * i + 1) * 64;            // odd tile (this iter)
        const int kE2 = ((2 * i + 2) & 63) * 64;     // next even tile
        const int kO2 = ((2 * i + 3) & 63) * 64;     // next odd tile
        // P1
        LOAD_A(0, 0); LOAD_B(0, 0); STAGE_A(1, 0, kO);
        BAR(); MFMA8(0, 0); BAR();
        // P2
        LOAD_B(0, 1); STAGE_A(1, 1, kO);
        BAR(); MFMA8(0, 1); BAR();
        // P3
        LOAD_A(0, 1); STAGE_B(0, 0, kE2);
        BAR(); MFMA8(1, 1); BAR();
        // P4
        STAGE_B(0, 1, kE2);
        BAR(); MFMA8(1, 0);
        VMCNT4();
        BAR();
        __builtin_amdgcn_sched_barrier(0);
        // P5
        LOAD_A(1, 0); LOAD_B(1, 0); STAGE_A(0, 0, kE2);
        BAR(); MFMA8(0, 0); BAR();
        // P6
        LOAD_B(1, 1); STAGE_A(0, 1, kE2);
        BAR(); MFMA8(0, 1); BAR();
        // P7
        LOAD_A(1, 1); STAGE_B(1, 0, kO2);
        BAR(); MFMA8(1, 1); BAR();
        // P8
        STAGE_B(1, 1, kO2);
        BAR(); MFMA8(1, 0);
        VMCNT4();
        BAR();
        __builtin_amdgcn_sched_barrier(0);
    }

    // ---- fused epilogue: C/D col=lane&15 (=j), row=(lane>>4)*4+reg (=m) ----
    const int cr = lg * 4;
    const int jcol = j0 + wc * 16 + lm;
    const size_t bh = (size_t)M_SZ * H_SZ;
    const float bz  = Bias[jcol];
    const float biv = Bias[H_SZ + jcol];
    const float bfv = Bias[2 * H_SZ + jcol];
    const float bov = Bias[3 * H_SZ + jcol];
#pragma unroll
    for (int mi = 0; mi < 8; ++mi) {
#pragma unroll
        for (int r = 0; r < 4; ++r) {
            const int mrow = m0 + wr * 128 + mi * 16 + cr + r;
            const size_t off = (size_t)mrow * H_SZ + jcol;
            float z  = acc[mi][0][r] + bz;
            float iv = acc[mi][1][r] + biv;
            float f  = acc[mi][2][r] + bfv;
            float o  = acc[mi][3][r] + bov;
            float z_t = 1.0f - 2.0f * frcp(fexp(2.0f * z) + 1.0f);
            float f_t = frcp(1.0f + fexp(-f));
            float o_t = frcp(1.0f + fexp(-o));
            float ls  = fminf(f, 0.0f) - flog1p(fexp(-fabsf(f)));
            float m_t = fmaxf(ls + Mst[off], iv);
            float ip  = fexp(iv - m_t);
            float c_t = f_t * Cst[off] + ip * z_t;
            float n_t = f_t * Nst[off] + ip;
            float h_t = o_t * c_t * frcp(n_t);
            out[off]          = h_t;
            out[bh + off]     = c_t;
            out[2 * bh + off] = n_t;
            out[3 * bh + off] = m_t;
        }
    }
}

// ---------------------------------------------------------------------------
extern "C" void kernel_launch(void* const* d_in, const int* in_sizes, int n_in,
                              void* d_out, int out_size, void* d_ws, size_t ws_size,
                              hipStream_t stream) {
    const float* x    = (const float*)d_in[0];
    const float* h    = (const float*)d_in[1];
    const float* c    = (const float*)d_in[2];
    const float* n    = (const float*)d_in[3];
    const float* m    = (const float*)d_in[4];
    const float* W    = (const float*)d_in[5];
    const float* Bias = (const float*)d_in[6];
    float* out = (float*)d_out;

    const size_t WT_BYTES = (size_t)N_SZ * K_SZ * 2;
    const size_t A_BYTES  = (size_t)M_SZ * K_SZ * 2;
    if (ws_size < WT_BYTES + A_BYTES) return;

    char* ws = (char*)d_ws;
    _Float16* Wt = (_Float16*)ws;
    _Float16* A  = (_Float16*)(ws + WT_BYTES);

    hipError_t attr_ok = hipFuncSetAttribute(
        reinterpret_cast<const void*>(gemm8_fused),
        hipFuncAttributeMaxDynamicSharedMemorySize, 131072);

    cast_combined_kernel<<<16384, 256, 0, stream>>>(x, h, A);
    transpose_cast_W<<<dim3(128, 64), 256, 0, stream>>>(W, Wt);
    if (attr_ok == hipSuccess) {
        gemm8_fused<<<dim3(32, 16), 512, 131072, stream>>>(A, Wt, Bias, c, n, m, out);
    } else {
        gemm_fused_kernel<<<dim3(64, 32), 256, 0, stream>>>(A, Wt, Bias, c, n, m, out);
    }
}

// Round 5
// 568.257 us; speedup vs baseline: 1.2343x; 1.0120x over previous
//
#include <hip/hip_runtime.h>
#include <hip/hip_fp16.h>

#define M_SZ 4096
#define I_SZ 2048
#define H_SZ 2048
#define K_SZ 4096   // I + H
#define N_SZ 8192   // 4 * H

typedef _Float16 half8_t __attribute__((ext_vector_type(8)));
typedef _Float16 half4_t __attribute__((ext_vector_type(4)));
typedef float    f32x4   __attribute__((ext_vector_type(4)));

typedef const void __attribute__((address_space(1)))* gas_ptr;
typedef void       __attribute__((address_space(3)))* las_ptr;

__device__ __forceinline__ void async_load16(const void* g, void* l) {
    // width-16 global->LDS DMA; LDS dest is wave-uniform base + lane*16
    __builtin_amdgcn_global_load_lds((gas_ptr)g, (las_ptr)l, 16, 0, 0);
}

__device__ __forceinline__ float fexp(float x) {
    return __builtin_amdgcn_exp2f(x * 1.44269504088896340736f);
}
__device__ __forceinline__ float frcp(float x) { return __builtin_amdgcn_rcpf(x); }
__device__ __forceinline__ float flog1p(float t) {
    return __builtin_amdgcn_logf(1.0f + t) * 0.69314718055994530942f;
}

// ---------------------------------------------------------------------------
// Kernel 1 (fused prep, single launch): blocks [0,16384) cast concat(x,h) ->
// fp16 A; blocks [16384, 24576) transpose+cast W -> Wt. Independent halves
// overlap on different CUs instead of serializing as two launches.
// ---------------------------------------------------------------------------
__global__ __launch_bounds__(256)
void prep_kernel(const float* __restrict__ x,
                 const float* __restrict__ h,
                 _Float16* __restrict__ A,
                 const float* __restrict__ W,
                 _Float16* __restrict__ Wt) {
    __shared__ _Float16 sT[64 * 64];
    const int t = threadIdx.x;
    if (blockIdx.x < 16384) {
        // ---- cast_combined ----
        int idx = blockIdx.x * 256 + t;     // one float4 each
        int b   = idx >> 10;
        int c4  = idx & 1023;
        const float* src = (c4 < 512) ? (x + (size_t)b * I_SZ + c4 * 4)
                                      : (h + (size_t)b * H_SZ + (c4 - 512) * 4);
        f32x4 v = *(const f32x4*)src;
        half4_t o = { (_Float16)v[0], (_Float16)v[1], (_Float16)v[2], (_Float16)v[3] };
        *(half4_t*)(A + (size_t)b * K_SZ + c4 * 4) = o;
    } else {
        // ---- transpose_cast_W: 64k x 64n tile via LDS ----
        const int bx = blockIdx.x - 16384;
        const int nb = (bx & 127) * 64;
        const int kb = (bx >> 7) * 64;
        const int k0 = (t >> 4) * 4;
        const int n4 = (t & 15) * 4;

        f32x4 v[4];
#pragma unroll
        for (int p = 0; p < 4; ++p)
            v[p] = *(const f32x4*)(W + (size_t)(kb + k0 + p) * N_SZ + nb + n4);
#pragma unroll
        for (int j = 0; j < 4; ++j) {
            half4_t hv = { (_Float16)v[0][j], (_Float16)v[1][j],
                           (_Float16)v[2][j], (_Float16)v[3][j] };
            const int n = n4 + j;
            const int c = (k0 >> 2) ^ (n & 15);
            *(half4_t*)(sT + n * 64 + c * 4) = hv;
        }
        __syncthreads();
#pragma unroll
        for (int p = 0; p < 2; ++p) {
            const int n  = (t >> 3) + p * 32;
            const int c0 = ((t & 7) * 2)     ^ (n & 15);
            const int c1 = ((t & 7) * 2 + 1) ^ (n & 15);
            half4_t lo = *(const half4_t*)(sT + n * 64 + c0 * 4);
            half4_t hi = *(const half4_t*)(sT + n * 64 + c1 * 4);
            half8_t o = { lo[0], lo[1], lo[2], lo[3], hi[0], hi[1], hi[2], hi[3] };
            *(half8_t*)(Wt + (size_t)(nb + n) * K_SZ + kb + (t & 7) * 8) = o;
        }
    }
}

// ---------------------------------------------------------------------------
// Kernel 3a (FALLBACK, R2-passing): 128x128 2-phase fused GEMM + pointwise.
// ---------------------------------------------------------------------------
__global__ __launch_bounds__(256)
void gemm_fused_kernel(const _Float16* __restrict__ A,
                       const _Float16* __restrict__ Wt,
                       const float* __restrict__ Bias,
                       const float* __restrict__ Cst,
                       const float* __restrict__ Nst,
                       const float* __restrict__ Mst,
                       float* __restrict__ out) {
    __shared__ _Float16 sA[128 * 32];
    __shared__ _Float16 sB[128 * 32];
    const int t    = threadIdx.x;
    const int wave = t >> 6;
    const int lane = t & 63;
    const int m0 = blockIdx.y * 128;
    const int j0 = blockIdx.x * 32;

    f32x4 acc[4][4] = {};

    const int srl   = lane >> 2;
    const int chunk = (lane & 3) ^ ((lane >> 3) & 3);
    const int ar0 = wave * 16 + srl;
    const int br0 = wave * 16 + srl;
    const int gb  = (br0 >> 4) & 3;
    const int wrow0 = gb * H_SZ + j0 + (br0 & 15);

    const _Float16* gA0 = A  + (size_t)(m0 + ar0) * K_SZ + chunk * 8;
    const _Float16* gA1 = gA0 + (size_t)64 * K_SZ;
    const _Float16* gB0 = Wt + (size_t)wrow0 * K_SZ + chunk * 8;
    const _Float16* gB1 = gB0 + (size_t)16 * K_SZ;
    char* lA0 = (char*)sA + wave * 1024;
    char* lA1 = lA0 + 4096;
    char* lB0 = (char*)sB + wave * 1024;
    char* lB1 = lB0 + 4096;

    const int lm    = lane & 15;
    const int slot  = (lane >> 4) ^ ((lm >> 1) & 3);
    const int wm    = (wave >> 1) * 64;
    const int jhalf = wave & 1;
    const _Float16* fA = sA + (wm + lm) * 32 + slot * 8;
    const _Float16* fB = sB + (jhalf * 64 + lm) * 32 + slot * 8;

    for (int k0 = 0; k0 < K_SZ; k0 += 32) {
        async_load16(gA0 + k0, lA0);
        async_load16(gA1 + k0, lA1);
        async_load16(gB0 + k0, lB0);
        async_load16(gB1 + k0, lB1);
        __syncthreads();

        half8_t af[4], bf[4];
#pragma unroll
        for (int mi = 0; mi < 4; ++mi)
            af[mi] = *(const half8_t*)(fA + mi * 16 * 32);
#pragma unroll
        for (int ni = 0; ni < 4; ++ni)
            bf[ni] = *(const half8_t*)(fB + ni * 16 * 32);
#pragma unroll
        for (int mi = 0; mi < 4; ++mi)
#pragma unroll
            for (int ni = 0; ni < 4; ++ni)
                acc[mi][ni] = __builtin_amdgcn_mfma_f32_16x16x32_f16(
                    af[mi], bf[ni], acc[mi][ni], 0, 0, 0);
        __syncthreads();
    }

    const int cr = (lane >> 4) * 4;
    const int cc = lane & 15;
    const int jcol = j0 + jhalf * 16 + cc;
    const size_t bh = (size_t)M_SZ * H_SZ;
    const float bz  = Bias[jcol];
    const float bi  = Bias[H_SZ + jcol];
    const float bff = Bias[2 * H_SZ + jcol];
    const float bo  = Bias[3 * H_SZ + jcol];
#pragma unroll
    for (int mi = 0; mi < 4; ++mi) {
#pragma unroll
        for (int r = 0; r < 4; ++r) {
            const int m = m0 + wm + mi * 16 + cr + r;
            const size_t off = (size_t)m * H_SZ + jcol;
            float z = acc[mi][0][r] + bz;
            float i = acc[mi][1][r] + bi;
            float f = acc[mi][2][r] + bff;
            float o = acc[mi][3][r] + bo;
            float z_t = 1.0f - 2.0f * frcp(fexp(2.0f * z) + 1.0f);
            float f_t = frcp(1.0f + fexp(-f));
            float o_t = frcp(1.0f + fexp(-o));
            float ls  = fminf(f, 0.0f) - flog1p(fexp(-fabsf(f)));
            float m_t = fmaxf(ls + Mst[off], i);
            float ip  = fexp(i - m_t);
            float c_t = f_t * Cst[off] + ip * z_t;
            float n_t = f_t * Nst[off] + ip;
            float h_t = o_t * c_t * frcp(n_t);
            out[off]          = h_t;
            out[bh + off]     = c_t;
            out[2 * bh + off] = n_t;
            out[3 * bh + off] = m_t;
        }
    }
}

// ---------------------------------------------------------------------------
// Kernel 3b: 256x256 8-phase fused GEMM + sLSTM pointwise (T1+T2+T3+T4+T5).
//
// Tile 256m x 256cols (64 j x 4 gates), BK=64, 8 waves (2M x 4N), 512 thr.
// B tile row r -> Wt row n(r) = ((r>>4)&3)*2048 + j0 + (r&15) + (r>>6)*16.
// LDS 128 KiB: 2 dbuf x [256 rows][64 k] x (A,B); chunk c of row r at slot
// c^(r&7) via pre-swizzled global source; read slot (ks*4+lg)^(lm&7).
// T1 (R4 rev): partition grid by j-column per XCD — each XCD owns 4 whole
// j-columns (64 blocks = 4j x 16m; concurrent set 2j x 16m) so the
// concurrent Wt working set per XCD is 4 MB (L2-resident, fetched once)
// and A (32 MB, read by all XCDs) stays L3-resident. Was: 1 m-tile x 32 j
// per XCD -> 64 MB concurrent Wt/XCD -> 415 MB HBM over-fetch (R4 PMC).
// ---------------------------------------------------------------------------
#define BAR() __builtin_amdgcn_s_barrier()

#define LOAD_A(d, qm) do { \
    _Pragma("unroll") \
    for (int mi_ = 0; mi_ < 4; ++mi_) { \
        const _Float16* p_ = sA + (d)*16384 + (wr*128 + ((qm)*4+mi_)*16 + lm)*64; \
        a[mi_][0] = *(const half8_t*)(p_ + slot0*8); \
        a[mi_][1] = *(const half8_t*)(p_ + slot1*8); \
    } } while(0)

#define LOAD_B(d, qn) do { \
    _Pragma("unroll") \
    for (int ni_ = 0; ni_ < 2; ++ni_) { \
        const _Float16* p_ = sB + (d)*16384 + (wc*64 + ((qn)*2+ni_)*16 + lm)*64; \
        b[(qn)*2+ni_][0] = *(const half8_t*)(p_ + slot0*8); \
        b[(qn)*2+ni_][1] = *(const half8_t*)(p_ + slot1*8); \
    } } while(0)

#define MFMA8(qm, qn) do { \
    __builtin_amdgcn_s_setprio(1); \
    _Pragma("unroll") \
    for (int mi_ = 0; mi_ < 4; ++mi_) { \
        _Pragma("unroll") \
        for (int ni_ = 0; ni_ < 2; ++ni_) { \
            acc[(qm)*4+mi_][(qn)*2+ni_] = __builtin_amdgcn_mfma_f32_16x16x32_f16( \
                a[mi_][0], b[(qn)*2+ni_][0], acc[(qm)*4+mi_][(qn)*2+ni_], 0, 0, 0); \
            acc[(qm)*4+mi_][(qn)*2+ni_] = __builtin_amdgcn_mfma_f32_16x16x32_f16( \
                a[mi_][1], b[(qn)*2+ni_][1], acc[(qm)*4+mi_][(qn)*2+ni_], 0, 0, 0); \
        } } \
    __builtin_amdgcn_s_setprio(0); \
} while(0)

#define STAGE_A(d, h, kt) do { \
    char* ba_ = (char*)sA + (d)*32768 + ((h)*128 + wid*16)*128; \
    async_load16(pA0 + (size_t)(h)*(128*K_SZ) + (kt), ba_); \
    async_load16(pA1 + (size_t)(h)*(128*K_SZ) + (kt), ba_ + 1024); \
} while(0)

#define STAGE_B(d, h, kt) do { \
    char* bb_ = (char*)sB + (d)*32768 + ((h)*128 + wid*16)*128; \
    async_load16(pB0 + (size_t)(h)*(32*K_SZ) + (kt), bb_); \
    async_load16(pB1 + (size_t)(h)*(32*K_SZ) + (kt), bb_ + 1024); \
} while(0)

#define VMCNT4() do { \
    asm volatile("s_waitcnt vmcnt(4)" ::: "memory"); \
} while(0)

__global__ __launch_bounds__(512, 2)
void gemm8_fused(const _Float16* __restrict__ A,
                 const _Float16* __restrict__ Wt,
                 const float* __restrict__ Bias,
                 const float* __restrict__ Cst,
                 const float* __restrict__ Nst,
                 const float* __restrict__ Mst,
                 float* __restrict__ out) {
    extern __shared__ char lds[];
    _Float16* sA = (_Float16*)lds;                 // [2][256][64]
    _Float16* sB = (_Float16*)(lds + 65536);       // [2][256][64]

    const int t    = threadIdx.x;
    const int wid  = t >> 6;
    const int lane = t & 63;

    // T1 (j-partitioned): xcd = flat&7 owns j-tiles [xcd*4, xcd*4+4), m cycling
    const int flat = blockIdx.y * 32 + blockIdx.x;       // 0..511
    const int q    = flat >> 3;                          // 0..63 within XCD
    const int jt   = (flat & 7) * 4 + (q >> 4);          // 0..31
    const int mt   = q & 15;                             // 0..15
    const int m0 = mt * 256;
    const int j0 = jt * 64;

    const int wr = wid >> 2, wc = wid & 3;
    const int lm = lane & 15, lg = lane >> 4;
    const int slot0 = lg ^ (lm & 7);          // read slot, ks=0
    const int slot1 = slot0 ^ 4;              // ks=1

    f32x4 acc[8][4] = {};
    half8_t a[4][2], b[4][2];

    // ---- staging source addrs (pre-swizzled: lane fetches chunk (l&7)^(l>>3)) ----
    const int l8 = lane >> 3, s8 = lane & 7;
    const int cS = s8 ^ l8;                   // global k-chunk this lane fetches
    const int rq0 = wid * 16 + l8;            // row-in-half, load q=0
    const int rq1 = rq0 + 8;                  // load q=1
    const int nB0 = ((rq0 >> 4) & 3) * H_SZ + j0 + (rq0 & 15) + (rq0 >> 6) * 16;
    const int nB1 = ((rq1 >> 4) & 3) * H_SZ + j0 + (rq1 & 15) + (rq1 >> 6) * 16;

    const _Float16* pA0 = A  + (size_t)(m0 + rq0) * K_SZ + cS * 8;
    const _Float16* pA1 = A  + (size_t)(m0 + rq1) * K_SZ + cS * 8;
    const _Float16* pB0 = Wt + (size_t)nB0 * K_SZ + cS * 8;
    const _Float16* pB1 = Wt + (size_t)nB1 * K_SZ + cS * 8;

    // ---- prologue: tile0 (buf0, all 4 halves) + tile1 B halves (buf1) ----
    STAGE_A(0, 0, 0);  STAGE_A(0, 1, 0);
    STAGE_B(0, 0, 0);  STAGE_B(0, 1, 0);
    STAGE_B(1, 0, 64); STAGE_B(1, 1, 64);
    VMCNT4();
    BAR();
    __builtin_amdgcn_sched_barrier(0);

#pragma unroll 1
    for (int i = 0; i < 32; ++i) {
        const int kO  = (2 * i + 1) * 64;            // odd tile (this iter)
        const int kE2 = ((2 * i + 2) & 63) * 64;     // next even tile
        const int kO2 = ((2 * i + 3) & 63) * 64;     // next odd tile
        // P1
        LOAD_A(0, 0); LOAD_B(0, 0); STAGE_A(1, 0, kO);
        BAR(); MFMA8(0, 0); BAR();
        // P2
        LOAD_B(0, 1); STAGE_A(1, 1, kO);
        BAR(); MFMA8(0, 1); BAR();
        // P3
        LOAD_A(0, 1); STAGE_B(0, 0, kE2);
        BAR(); MFMA8(1, 1); BAR();
        // P4
        STAGE_B(0, 1, kE2);
        BAR(); MFMA8(1, 0);
        VMCNT4();
        BAR();
        __builtin_amdgcn_sched_barrier(0);
        // P5
        LOAD_A(1, 0); LOAD_B(1, 0); STAGE_A(0, 0, kE2);
        BAR(); MFMA8(0, 0); BAR();
        // P6
        LOAD_B(1, 1); STAGE_A(0, 1, kE2);
        BAR(); MFMA8(0, 1); BAR();
        // P7
        LOAD_A(1, 1); STAGE_B(1, 0, kO2);
        BAR(); MFMA8(1, 1); BAR();
        // P8
        STAGE_B(1, 1, kO2);
        BAR(); MFMA8(1, 0);
        VMCNT4();
        BAR();
        __builtin_amdgcn_sched_barrier(0);
    }

    // ---- fused epilogue: C/D col=lane&15 (=j), row=(lane>>4)*4+reg (=m) ----
    const int cr = lg * 4;
    const int jcol = j0 + wc * 16 + lm;
    const size_t bh = (size_t)M_SZ * H_SZ;
    const float bz  = Bias[jcol];
    const float biv = Bias[H_SZ + jcol];
    const float bfv = Bias[2 * H_SZ + jcol];
    const float bov = Bias[3 * H_SZ + jcol];
#pragma unroll
    for (int mi = 0; mi < 8; ++mi) {
#pragma unroll
        for (int r = 0; r < 4; ++r) {
            const int mrow = m0 + wr * 128 + mi * 16 + cr + r;
            const size_t off = (size_t)mrow * H_SZ + jcol;
            float z  = acc[mi][0][r] + bz;
            float iv = acc[mi][1][r] + biv;
            float f  = acc[mi][2][r] + bfv;
            float o  = acc[mi][3][r] + bov;
            float z_t = 1.0f - 2.0f * frcp(fexp(2.0f * z) + 1.0f);
            float f_t = frcp(1.0f + fexp(-f));
            float o_t = frcp(1.0f + fexp(-o));
            float ls  = fminf(f, 0.0f) - flog1p(fexp(-fabsf(f)));
            float m_t = fmaxf(ls + Mst[off], iv);
            float ip  = fexp(iv - m_t);
            float c_t = f_t * Cst[off] + ip * z_t;
            float n_t = f_t * Nst[off] + ip;
            float h_t = o_t * c_t * frcp(n_t);
            out[off]          = h_t;
            out[bh + off]     = c_t;
            out[2 * bh + off] = n_t;
            out[3 * bh + off] = m_t;
        }
    }
}

// ---------------------------------------------------------------------------
extern "C" void kernel_launch(void* const* d_in, const int* in_sizes, int n_in,
                              void* d_out, int out_size, void* d_ws, size_t ws_size,
                              hipStream_t stream) {
    const float* x    = (const float*)d_in[0];
    const float* h    = (const float*)d_in[1];
    const float* c    = (const float*)d_in[2];
    const float* n    = (const float*)d_in[3];
    const float* m    = (const float*)d_in[4];
    const float* W    = (const float*)d_in[5];
    const float* Bias = (const float*)d_in[6];
    float* out = (float*)d_out;

    const size_t WT_BYTES = (size_t)N_SZ * K_SZ * 2;
    const size_t A_BYTES  = (size_t)M_SZ * K_SZ * 2;
    if (ws_size < WT_BYTES + A_BYTES) return;

    char* ws = (char*)d_ws;
    _Float16* Wt = (_Float16*)ws;
    _Float16* A  = (_Float16*)(ws + WT_BYTES);

    hipError_t attr_ok = hipFuncSetAttribute(
        reinterpret_cast<const void*>(gemm8_fused),
        hipFuncAttributeMaxDynamicSharedMemorySize, 131072);

    prep_kernel<<<24576, 256, 0, stream>>>(x, h, A, W, Wt);
    if (attr_ok == hipSuccess) {
        gemm8_fused<<<dim3(32, 16), 512, 131072, stream>>>(A, Wt, Bias, c, n, m, out);
    } else {
        gemm_fused_kernel<<<dim3(64, 32), 256, 0, stream>>>(A, Wt, Bias, c, n, m, out);
    }
}